// Round 1
// baseline (112279.785 us; speedup 1.0000x reference)
//
#include <hip/hip_runtime.h>
#include <math.h>

typedef long long i64;

// ---------------------------------------------------------------------------
// Reduction helpers (256-thread block = 4 waves of 64)
// ---------------------------------------------------------------------------
__device__ __forceinline__ float waveReduceSum(float v){
#pragma unroll
  for(int o=32;o>0;o>>=1) v += __shfl_down(v,o,64);
  return v;
}
__device__ __forceinline__ float waveReduceMin(float v){
#pragma unroll
  for(int o=32;o>0;o>>=1) v = fminf(v, __shfl_down(v,o,64));
  return v;
}
__device__ __forceinline__ float waveReduceMax(float v){
#pragma unroll
  for(int o=32;o>0;o>>=1) v = fmaxf(v, __shfl_down(v,o,64));
  return v;
}
__device__ __forceinline__ float blockReduceSum256(float val, float* red){
  __syncthreads();
  val = waveReduceSum(val);
  if((threadIdx.x&63)==0) red[threadIdx.x>>6]=val;
  __syncthreads();
  return red[0]+red[1]+red[2]+red[3];
}
__device__ __forceinline__ float blockReduceMin256(float val, float* red){
  __syncthreads();
  val = waveReduceMin(val);
  if((threadIdx.x&63)==0) red[threadIdx.x>>6]=val;
  __syncthreads();
  return fminf(fminf(red[0],red[1]),fminf(red[2],red[3]));
}
__device__ __forceinline__ float blockReduceMax256(float val, float* red){
  __syncthreads();
  val = waveReduceMax(val);
  if((threadIdx.x&63)==0) red[threadIdx.x>>6]=val;
  __syncthreads();
  return fmaxf(fmaxf(red[0],red[1]),fmaxf(red[2],red[3]));
}

// ---------------------------------------------------------------------------
// Generic strided 2D copy: dst[doff + r*dld + c] = src[soff + r*sld + c]
// ---------------------------------------------------------------------------
__global__ __launch_bounds__(256) void fd_copyblk(
    float* __restrict__ dst, int dld, i64 doff,
    const float* __restrict__ src, int sld, i64 soff,
    int rows, int cols)
{
  i64 tot = (i64)rows*cols;
  for(i64 id = (i64)blockIdx.x*256 + threadIdx.x; id < tot; id += (i64)gridDim.x*256){
    int r = (int)(id / cols), c = (int)(id % cols);
    dst[doff + (i64)r*dld + c] = src[soff + (i64)r*sld + c];
  }
}

// ---------------------------------------------------------------------------
// Column scale: out (rows x 128) = in * diag(w)
// ---------------------------------------------------------------------------
__global__ __launch_bounds__(256) void fd_colscale(
    const float* __restrict__ in, const float* __restrict__ w,
    float* __restrict__ out, int rows)
{
  int tot = rows*128;
  for(int id = blockIdx.x*256 + threadIdx.x; id < tot; id += gridDim.x*256)
    out[id] = in[id] * w[id & 127];
}

// ---------------------------------------------------------------------------
// Generic fp32 GEMM: C = alpha*op(A)op(B) [+C if betaone] [+bias bcast over rows]
// tA: A stored K x M (row-major);  else M x K.  tB: B stored N x K; else K x N.
// grid = (M/64, N/64, kchunks). useAtomic -> atomicAdd into C (pre-zeroed).
// All dims multiples of 64 (M,N) and 16*gridDim.z (K) by construction.
// ---------------------------------------------------------------------------
__global__ __launch_bounds__(256) void fd_gemm(
    const float* __restrict__ A, const float* __restrict__ B,
    float* __restrict__ C, const float* __restrict__ bias,
    int M, int N, int K, int lda, int ldb, int ldc,
    int tA, int tB, float alpha, int betaone, int useAtomic)
{
  __shared__ float As[16][68];
  __shared__ float Bs[16][68];
  int bm = blockIdx.x*64, bn = blockIdx.y*64;
  int kchunk = K / gridDim.z;
  int k0 = blockIdx.z * kchunk;
  int tn = threadIdx.x & 15, tm = threadIdx.x >> 4;
  float acc[4][4] = {{0.f}};
  for(int kt = k0; kt < k0 + kchunk; kt += 16){
    if(tA){
      for(int l=threadIdx.x; l<1024; l+=256){ int kk=l>>6, mm=l&63;
        As[kk][mm] = A[(i64)(kt+kk)*lda + bm+mm]; }
    }else{
      for(int l=threadIdx.x; l<1024; l+=256){ int mm=l>>4, kk=l&15;
        As[kk][mm] = A[(i64)(bm+mm)*lda + kt+kk]; }
    }
    if(tB){
      for(int l=threadIdx.x; l<1024; l+=256){ int nn=l>>4, kk=l&15;
        Bs[kk][nn] = B[(i64)(bn+nn)*ldb + kt+kk]; }
    }else{
      for(int l=threadIdx.x; l<1024; l+=256){ int kk=l>>6, nn=l&63;
        Bs[kk][nn] = B[(i64)(kt+kk)*ldb + bn+nn]; }
    }
    __syncthreads();
#pragma unroll
    for(int kk=0; kk<16; kk++){
      float a[4], b[4];
#pragma unroll
      for(int i=0;i<4;i++){ a[i]=As[kk][tm*4+i]; b[i]=Bs[kk][tn*4+i]; }
#pragma unroll
      for(int i=0;i<4;i++)
#pragma unroll
        for(int j=0;j<4;j++) acc[i][j] += a[i]*b[j];
    }
    __syncthreads();
  }
#pragma unroll
  for(int i=0;i<4;i++){
    int row = bm + tm*4 + i;
#pragma unroll
    for(int j=0;j<4;j++){
      int col = bn + tn*4 + j;
      i64 idx = (i64)row*ldc + col;
      float v = alpha*acc[i][j];
      if(useAtomic){ atomicAdd(&C[idx], v); }
      else{
        if(betaone) v += C[idx];
        if(bias)    v += bias[col];
        C[idx] = v;
      }
    }
  }
}

// ---------------------------------------------------------------------------
// Cholesky of a 128x128 SPD block (packed-lower in LDS), regularized.
// Reads G (lower part) at (gld,goff); writes dense lower L (zeros above).
// One block, 256 threads.
// ---------------------------------------------------------------------------
__global__ __launch_bounds__(256) void fd_chol128(
    const float* __restrict__ G, int gld, i64 goff,
    float* __restrict__ L, int lld, i64 loff)
{
  __shared__ float P[8256];     // packed lower: row i at i*(i+1)/2
  __shared__ float colv[128];
  __shared__ float sc[2];
  int t = threadIdx.x;
  for(int i=t;i<128;i+=256){
    int base = i*(i+1)/2;
    for(int j=0;j<=i;j++) P[base+j] = G[goff + (i64)i*gld + j];
  }
  __syncthreads();
  if(t==0){
    float m=0.f;
    for(int i=0;i<128;i++){ float dd=P[i*(i+1)/2+i]; if(dd>m) m=dd; }
    if(!(m>0.f)) m = 1e-20f;
    sc[0] = m*4e-6f;   // diagonal regularization
    sc[1] = m*1e-8f;   // pivot floor
  }
  __syncthreads();
  float reg = sc[0], flo = sc[1];
  for(int i=t;i<128;i+=256) P[i*(i+1)/2+i] += reg;
  __syncthreads();
  for(int j=0;j<128;j++){
    int jb = j*(j+1)/2;
    if(t==0){
      float dd = fmaxf(P[jb+j], flo);
      float piv = sqrtf(dd);
      P[jb+j] = piv;
      colv[j] = piv;
    }
    __syncthreads();
    float pr = 1.f/colv[j];
    for(int i=j+1+t; i<128; i+=256){
      int base = i*(i+1)/2;
      float v = P[base+j]*pr;
      P[base+j] = v;
      colv[i] = v;
    }
    __syncthreads();
    for(int i=j+1+t; i<128; i+=256){
      int base = i*(i+1)/2;
      float ci = colv[i];
      for(int kx=j+1; kx<=i; kx++) P[base+kx] -= ci*colv[kx];
    }
    __syncthreads();
  }
  for(int i=t;i<128;i+=256){
    int base = i*(i+1)/2;
    for(int j=0;j<=i;j++)      L[loff + (i64)i*lld + j] = P[base+j];
    for(int j=i+1;j<128;j++)   L[loff + (i64)i*lld + j] = 0.f;
  }
}

// ---------------------------------------------------------------------------
// X = (L^T)^{-1} (upper 128x128, dense row-major). Thread k solves column k.
// ---------------------------------------------------------------------------
__global__ __launch_bounds__(128) void fd_trinv128(
    const float* __restrict__ L, int lld, i64 loff, float* __restrict__ X)
{
  int k = threadIdx.x;
  for(int i=k+1;i<128;i++) X[(i64)i*128 + k] = 0.f;
  X[(i64)k*128 + k] = 1.f / L[loff + (i64)k*lld + k];
  for(int i=k-1;i>=0;i--){
    float s = 0.f;
    for(int j=i+1;j<=k;j++) s += L[loff + (i64)j*lld + i] * X[(i64)j*128 + k];
    X[(i64)i*128 + k] = -s / L[loff + (i64)i*lld + i];
  }
}

// ---------------------------------------------------------------------------
// Householder tridiagonalization of symmetric 256x256 A (in global, destroyed).
// Writes d[256], e[256] (e[j]=subdiag), and unit Householder vectors Vh[j][0:256]
// (zeros for rows <= j). One block, 256 threads (thread t <-> row t).
// A = Q T Q^T with Q = H_0 H_1 ... H_253.
// ---------------------------------------------------------------------------
__global__ __launch_bounds__(256) void fd_tridiag(
    float* __restrict__ A, float* __restrict__ dT,
    float* __restrict__ eT, float* __restrict__ Vh)
{
  const int n = 256;
  __shared__ float v[256], w[256];
  __shared__ float red[8];
  __shared__ float sc[2];
  int t = threadIdx.x;
  for(int j=0;j<n-2;j++){
    float xi = (t>j)? A[(i64)t*n + j] : 0.f;
    float nrm2 = blockReduceSum256(xi*xi, red);
    if(t==0){
      float x0 = A[(i64)(j+1)*n + j];
      float nr = sqrtf(nrm2);
      float beta = (x0>=0.f)? -nr : nr;
      eT[j] = beta;
      float vn2 = 2.f*nrm2 - 2.f*beta*x0;
      sc[0]=beta; sc[1] = (vn2>1e-30f)? rsqrtf(vn2) : 0.f;
    }
    __syncthreads();
    float beta=sc[0], vs=sc[1];
    float vt = (t>j)? (xi - ((t==j+1)? beta : 0.f))*vs : 0.f;
    v[t]=vt;
    Vh[(i64)j*n + t] = vt;
    __syncthreads();
    float ut=0.f;
    if(t>j){
      const float* __restrict__ row = A + (i64)t*n;
      for(int k=j+1;k<n;k++) ut += row[k]*v[k];
    }
    float gamma = blockReduceSum256(vt*ut, red);
    float wt = 2.f*ut - 2.f*gamma*vt;
    w[t]=wt;
    __syncthreads();
    if(t>j){
      float* __restrict__ row = A + (i64)t*n;
      for(int k=j+1;k<n;k++) row[k] -= vt*w[k] + wt*v[k];
    }
    __syncthreads();
  }
  dT[t] = A[(i64)t*n + t];
  if(t==0) eT[n-2] = A[(i64)(n-1)*n + (n-2)];
  if(t==1) eT[n-1] = 0.f;
}

// ---------------------------------------------------------------------------
// Bisection eigenvalues of tridiagonal T: lam[k] = k-th LARGEST, k=0..128.
// Then delta = sqrt(max(lam[128],0)) and shrink weights:
//  wfx[i] = s_i/lambda_i, wfy[i] = s_i/sigma_i, s_i = sqrt(max(sigma_i-delta,0)).
// One block, 256 threads.
// ---------------------------------------------------------------------------
__global__ __launch_bounds__(256) void fd_bisect(
    const float* __restrict__ dT, const float* __restrict__ eT,
    float* __restrict__ lam, float* __restrict__ wfx, float* __restrict__ wfy)
{
  __shared__ float d[256], e2[256], eabs[256];
  __shared__ float red[8];
  __shared__ float sgl, sgh, spm, sdel;
  int t = threadIdx.x;
  d[t] = dT[t];
  float ev = (t<255)? eT[t] : 0.f;
  e2[t] = ev*ev; eabs[t] = fabsf(ev);
  __syncthreads();
  float rr = ((t>0)? eabs[t-1] : 0.f) + eabs[t];
  float mn = blockReduceMin256(d[t]-rr, red);
  float mx = blockReduceMax256(d[t]+rr, red);
  if(t==0){
    sgl = mn; sgh = mx;
    float s = fmaxf(fabsf(mn), fabsf(mx));
    spm = fmaxf(1e-25f, 1e-12f*s);
  }
  __syncthreads();
  float glo=sgl, ghi=sgh, pivmin=spm;
  if(t<=128){
    int k = t;
    float lo=glo, hi=ghi;
    for(int it=0; it<42; it++){
      float mid = 0.5f*(lo+hi);
      int cnt=0;
      float q = d[0]-mid; if(q<0.f) cnt++;
      for(int i=1;i<256;i++){
        if(fabsf(q)<pivmin) q = -pivmin;
        q = (d[i]-mid) - e2[i-1]/q;
        if(q<0.f) cnt++;
      }
      if(cnt <= 255-k) lo=mid; else hi=mid;
    }
    lam[k] = lo;
  }
  __syncthreads();
  if(t==0) sdel = sqrtf(fmaxf(lam[128], 0.f));
  __syncthreads();
  if(t<128){
    float l = lam[t];
    float sg = sqrtf(fmaxf(l,0.f));
    float s2 = fmaxf(sg - sdel, 0.f);
    float s = sqrtf(s2);
    wfx[t] = (s2>0.f && l >1e-30f)? (s/l)  : 0.f;
    wfy[t] = (s2>0.f && sg>1e-30f)? (s/sg) : 0.f;
  }
}

// ---------------------------------------------------------------------------
// Inverse iteration (2 passes) for top-128 eigenvectors of tridiagonal T.
// Thread k owns vector k; partial-pivoted tridiagonal LU (LAPACK stein-style).
// Output Ut (256 x 128 row-major, column k = vector k), unit norm.
// ---------------------------------------------------------------------------
__global__ __launch_bounds__(128) void fd_invit(
    const float* __restrict__ dT, const float* __restrict__ eT,
    const float* __restrict__ lam, float* __restrict__ Ut,
    float* __restrict__ ud, float* __restrict__ ue, float* __restrict__ uf)
{
  __shared__ float d[256], e[256];
  int k = threadIdx.x;
  for(int i=k;i<256;i+=128){ d[i]=dT[i]; e[i]=(i<255)? eT[i] : 0.f; }
  __syncthreads();
  float scl = fmaxf(fabsf(lam[0]), 1e-20f);
  unsigned hh = (unsigned)k*2654435761u; hh ^= hh>>13; hh *= 1103515245u; hh ^= hh>>16;
  float pert = (float)(hh & 0xFFFFu) * (1.f/65536.f);
  float shift = lam[k] - scl*6e-7f*(0.25f + pert);
  float pivmin = 3e-7f*scl + 1e-30f;
#define AT(a,i) a[(i64)(i)*128 + k]
  for(int i=0;i<256;i++){
    unsigned z = ((unsigned)i*73856093u) ^ ((unsigned)k*19349663u);
    z ^= z>>13; z *= 2654435769u; z ^= z>>16;
    AT(Ut,i) = ((float)(z & 0xFFFFFFu) * (1.f/8388608.f)) - 1.f;
  }
  for(int pass=0; pass<2; pass++){
    float p = d[0]-shift, q = e[0], r = 0.f;
    for(int i=0;i<255;i++){
      float bel = e[i];
      float bn  = d[i+1]-shift;
      float cn  = (i+1<255)? e[i+1] : 0.f;
      float xi  = AT(Ut,i), xn = AT(Ut,i+1);
      if(fabsf(p) >= fabsf(bel)){
        float piv = (fabsf(p)<pivmin)? ((p<0.f)?-pivmin:pivmin) : p;
        float m = bel/piv;
        AT(ud,i)=piv; AT(ue,i)=q; AT(uf,i)=r;
        p = bn - m*q; q = cn - m*r; r = 0.f;
        AT(Ut,i+1) = xn - m*xi;
      } else {
        float piv = bel;
        float m = p/piv;
        AT(ud,i)=piv; AT(ue,i)=bn; AT(uf,i)=cn;
        p = q - m*bn; q = r - m*cn; r = 0.f;
        AT(Ut,i) = xn;
        AT(Ut,i+1) = xi - m*xn;
      }
    }
    {
      float piv = (fabsf(p)<pivmin)? ((p<0.f)?-pivmin:pivmin) : p;
      AT(ud,255)=piv;
    }
    float x1=0.f, x2=0.f, nrm2=0.f;
    for(int i=255;i>=0;i--){
      float s = AT(Ut,i);
      if(i<255) s -= AT(ue,i)*x1;
      if(i<254) s -= AT(uf,i)*x2;
      float x = s / AT(ud,i);
      x = fminf(fmaxf(x, -1e17f), 1e17f);
      AT(Ut,i) = x;
      x2=x1; x1=x;
      nrm2 += x*x;
    }
    float rn = rsqrtf(fmaxf(nrm2, 1e-30f));
    for(int i=0;i<256;i++) AT(Ut,i) *= rn;
  }
#undef AT
}

// ---------------------------------------------------------------------------
// Back-transform: Uout = Q * Uin, Q = H_0 ... H_253 (apply j=253..0).
// Uin/Uout: 256 x 128. 4 blocks x 32-column slabs, 256 threads each.
// ---------------------------------------------------------------------------
__global__ __launch_bounds__(256) void fd_applyq(
    const float* __restrict__ Vh, const float* __restrict__ Uin,
    float* __restrict__ Uout)
{
  __shared__ float S[256][33];
  __shared__ float v[256];
  __shared__ float part[8][32];
  __shared__ float wc[32];
  int c = threadIdx.x & 31, g = threadIdx.x >> 5;   // 8 row-groups of 32
  int cb = blockIdx.x*32;
  for(int i=g*32; i<g*32+32; i++) S[i][c] = Uin[(i64)i*128 + cb + c];
  __syncthreads();
  for(int j=253;j>=0;j--){
    v[threadIdx.x] = Vh[(i64)j*256 + threadIdx.x];
    __syncthreads();
    float pd = 0.f;
    for(int i=g*32;i<g*32+32;i++) pd += v[i]*S[i][c];
    part[g][c] = pd;
    __syncthreads();
    if(g==0){
      float s=0.f;
#pragma unroll
      for(int gg=0;gg<8;gg++) s += part[gg][c];
      wc[c] = 2.f*s;
    }
    __syncthreads();
    float wv = wc[c];
    for(int i=g*32;i<g*32+32;i++) S[i][c] -= v[i]*wv;
    __syncthreads();
  }
  for(int i=g*32;i<g*32+32;i++) Uout[(i64)i*128 + cb + c] = S[i][c];
}

// ---------------------------------------------------------------------------
// Host driver
// ---------------------------------------------------------------------------
extern "C" void kernel_launch(void* const* d_in, const int* in_sizes, int n_in,
                              void* d_out, int out_size, void* d_ws, size_t ws_size,
                              hipStream_t stream)
{
  const float* x    = (const float*)d_in[0];   // 8192 x 1280
  const float* wgt  = (const float*)d_in[1];   // 5120 x 1280
  const float* bias = (const float*)d_in[2];   // 5120
  float* out = (float*)d_out;

  const int m = 8192, p = 5120, ldx = 1280, nb = 10;

  // ---- scratch layout: everything dead-before-final lives inside d_out ----
  float* ob = (float*)d_out;
  i64 o = 0;
  float* Cx  = ob+o; o += (i64)m*256;
  float* Cy  = ob+o; o += (i64)p*256;
  float* Gxx = ob+o; o += 65536;
  float* Gyy = ob+o; o += 65536;
  float* Lx  = ob+o; o += 65536;
  float* Ly  = ob+o; o += 65536;
  float* Km  = ob+o; o += 65536;
  float* Am  = ob+o; o += 65536;
  float* Vh  = ob+o; o += 65536;
  float* Ssx = ob+o; o += 16384;
  float* Ssy = ob+o; o += 16384;
  float* Xx  = ob+o; o += 16384;
  float* Xy  = ob+o; o += 16384;
  float* Xq  = ob+o; o += 16384;
  float* G1q = ob+o; o += 16384;
  float* dT  = ob+o; o += 256;
  float* eT  = ob+o; o += 256;
  float* lam = ob+o; o += 256;
  float* wfx = ob+o; o += 128;
  float* wfy = ob+o; o += 128;
  float* Ut  = ob+o; o += 32768;
  float* Uo1 = ob+o; o += 32768;
  float* Uo  = ob+o; o += 32768;
  float* Ub  = ob+o; o += 32768;
  float* Pm  = ob+o; o += 32768;
  float* Pf  = ob+o; o += 32768;
  float* Uf  = ob+o; o += 32768;
  float* Mx  = ob+o; o += 32768;
  float* My  = ob+o; o += 32768;
  float* iud = ob+o; o += 32768;
  float* iue = ob+o; o += 32768;
  float* iuf = ob+o; o += 32768;
  // o ~ 4.4M floats << out_size (41.9M floats)

  // Bx/By must survive into the final GEMM (which overwrites d_out) -> d_ws
  float* ws = (float*)d_ws;
  float* Bx = ws;                       // 8192 x 128
  float* By = ws + (i64)m*128;          // 5120 x 128
  (void)ws_size; (void)out_size; (void)n_in; (void)in_sizes;

  auto GEMM = [&](const float* A, const float* B, float* C, const float* bs,
                  int M,int N,int K,int lda,int ldb,int ldc,int tA,int tB,
                  float alpha,int betaone,int atom,int kz){
    dim3 g(M/64, N/64, kz);
    hipLaunchKernelGGL(fd_gemm, g, dim3(256), 0, stream,
                       A,B,C,bs,M,N,K,lda,ldb,ldc,tA,tB,alpha,betaone,atom);
  };
  auto COPY = [&](float* dst,int dld,i64 doff,const float* src,int sld,i64 soff,
                  int rows,int cols){
    i64 tot=(i64)rows*cols; int g=(int)((tot+255)/256); if(g>4096) g=4096;
    hipLaunchKernelGGL(fd_copyblk, dim3(g), dim3(256), 0, stream,
                       dst,dld,doff,src,sld,soff,rows,cols);
  };
  auto Z = [&](float* ptr, i64 elems){ hipMemsetAsync(ptr, 0, (size_t)elems*4, stream); };

  for(int t=1;t<nb;t++){
    // ---- pack Cx = [Bx | x_t], Cy = [By | w_t] (step 1: Bx=x_0, By=w_0) ----
    if(t==1){ COPY(Cx,256,0, x,  ldx,0, m,128); COPY(Cy,256,0, wgt,ldx,0, p,128); }
    else    { COPY(Cx,256,0, Bx, 128,0, m,128); COPY(Cy,256,0, By, 128,0, p,128); }
    COPY(Cx,256,128, x,  ldx,(i64)t*128, m,128);
    COPY(Cy,256,128, wgt,ldx,(i64)t*128, p,128);

    // ---- Grams (split-K + atomics) ----
    Z(Gxx,65536); Z(Gyy,65536);
    GEMM(Cx,Cx,Gxx,nullptr, 256,256,8192, 256,256,256, 1,0, 1.f,0,1, 8);
    GEMM(Cy,Cy,Gyy,nullptr, 256,256,5120, 256,256,256, 1,0, 1.f,0,1, 5);

    // ---- blocked 256-Cholesky, x side: Gxx = Lx Lx^T ----
    Z(Lx,65536);
    hipLaunchKernelGGL(fd_chol128, dim3(1),dim3(256),0,stream, Gxx,256,(i64)0, Lx,256,(i64)0);
    hipLaunchKernelGGL(fd_trinv128,dim3(1),dim3(128),0,stream, Lx,256,(i64)0, Xx);
    GEMM(Gxx + (i64)128*256, Xx, Lx + (i64)128*256, nullptr,
         128,128,128, 256,128,256, 0,0, 1.f,0,0, 1);                 // L21 = G21 * (L11^T)^-1
    COPY(Ssx,128,0, Gxx,256,(i64)128*256+128, 128,128);              // S = G22
    GEMM(Lx + (i64)128*256, Lx + (i64)128*256, Ssx, nullptr,
         128,128,128, 256,256,128, 0,1, -1.f,1,0, 1);                // S -= L21 L21^T
    hipLaunchKernelGGL(fd_chol128, dim3(1),dim3(256),0,stream, Ssx,128,(i64)0,
                       Lx,256,(i64)128*256+128);

    // ---- y side: Gyy = Ly Ly^T ----
    Z(Ly,65536);
    hipLaunchKernelGGL(fd_chol128, dim3(1),dim3(256),0,stream, Gyy,256,(i64)0, Ly,256,(i64)0);
    hipLaunchKernelGGL(fd_trinv128,dim3(1),dim3(128),0,stream, Ly,256,(i64)0, Xy);
    GEMM(Gyy + (i64)128*256, Xy, Ly + (i64)128*256, nullptr,
         128,128,128, 256,128,256, 0,0, 1.f,0,0, 1);
    COPY(Ssy,128,0, Gyy,256,(i64)128*256+128, 128,128);
    GEMM(Ly + (i64)128*256, Ly + (i64)128*256, Ssy, nullptr,
         128,128,128, 256,256,128, 0,1, -1.f,1,0, 1);
    hipLaunchKernelGGL(fd_chol128, dim3(1),dim3(256),0,stream, Ssy,128,(i64)0,
                       Ly,256,(i64)128*256+128);

    // ---- core K = Rx Ry^T = Lx^T Ly ;  A = K K^T ----
    GEMM(Lx,Ly,Km,nullptr, 256,256,256, 256,256,256, 1,0, 1.f,0,0, 1);
    GEMM(Km,Km,Am,nullptr, 256,256,256, 256,256,256, 0,1, 1.f,0,0, 1);

    // ---- EVD of A: tridiag -> bisection -> inverse iteration ----
    hipLaunchKernelGGL(fd_tridiag, dim3(1),dim3(256),0,stream, Am,dT,eT,Vh);
    hipLaunchKernelGGL(fd_bisect,  dim3(1),dim3(256),0,stream, dT,eT,lam,wfx,wfy);
    hipLaunchKernelGGL(fd_invit,   dim3(1),dim3(128),0,stream, dT,eT,lam,Ut,iud,iue,iuf);

    // ---- CholQR2 on the 128 top T-basis vectors ----
    GEMM(Ut,Ut,G1q,nullptr, 128,128,256, 128,128,128, 1,0, 1.f,0,0, 1);
    hipLaunchKernelGGL(fd_chol128, dim3(1),dim3(256),0,stream, G1q,128,(i64)0, Ssx,128,(i64)0);
    hipLaunchKernelGGL(fd_trinv128,dim3(1),dim3(128),0,stream, Ssx,128,(i64)0, Xq);
    GEMM(Ut,Xq,Uo1,nullptr, 256,128,128, 128,128,128, 0,0, 1.f,0,0, 1);
    GEMM(Uo1,Uo1,G1q,nullptr, 128,128,256, 128,128,128, 1,0, 1.f,0,0, 1);
    hipLaunchKernelGGL(fd_chol128, dim3(1),dim3(256),0,stream, G1q,128,(i64)0, Ssx,128,(i64)0);
    hipLaunchKernelGGL(fd_trinv128,dim3(1),dim3(128),0,stream, Ssx,128,(i64)0, Xq);
    GEMM(Uo1,Xq,Uo,nullptr, 256,128,128, 128,128,128, 0,0, 1.f,0,0, 1);

    // ---- back-transform to original basis: Ub = Q_H * Uo ----
    hipLaunchKernelGGL(fd_applyq, dim3(4),dim3(256),0,stream, Vh,Uo,Ub);

    // ---- coefficient updates (all GEMMs, no triangular solves) ----
    GEMM(Km,Ub,Pm,nullptr, 256,128,256, 256,128,128, 1,0, 1.f,0,0, 1);   // P = K^T U
    hipLaunchKernelGGL(fd_colscale, dim3(128),dim3(256),0,stream, Pm,wfx,Pf,256);
    hipLaunchKernelGGL(fd_colscale, dim3(128),dim3(256),0,stream, Ub,wfy,Uf,256);
    GEMM(Ly,Pf,Mx,nullptr, 256,128,256, 256,128,128, 0,0, 1.f,0,0, 1);   // Mx = Ry^T P diag
    GEMM(Lx,Uf,My,nullptr, 256,128,256, 256,128,128, 0,0, 1.f,0,0, 1);   // My = Rx^T U diag

    GEMM(Cx,Mx,Bx,nullptr, 8192,128,256, 256,128,128, 0,0, 1.f,0,0, 1);  // Bx' = Cx Mx
    GEMM(Cy,My,By,nullptr, 5120,128,256, 256,128,128, 0,0, 1.f,0,0, 1);  // By' = Cy My
  }

  // ---- final: out = Bx By^T + bias (overwrites all of d_out) ----
  GEMM(Bx,By,out,bias, 8192,5120,128, 128,128,5120, 0,1, 1.f,0,0, 1);
}

// Round 2
// 67929.187 us; speedup vs baseline: 1.6529x; 1.6529x over previous
//
#include <hip/hip_runtime.h>
#include <math.h>

typedef long long i64;

// ---------------------------------------------------------------------------
// Reduction helpers (256-thread block = 4 waves of 64)
// ---------------------------------------------------------------------------
__device__ __forceinline__ float waveReduceSum(float v){
#pragma unroll
  for(int o=32;o>0;o>>=1) v += __shfl_down(v,o,64);
  return v;
}
__device__ __forceinline__ float waveReduceMin(float v){
#pragma unroll
  for(int o=32;o>0;o>>=1) v = fminf(v, __shfl_down(v,o,64));
  return v;
}
__device__ __forceinline__ float waveReduceMax(float v){
#pragma unroll
  for(int o=32;o>0;o>>=1) v = fmaxf(v, __shfl_down(v,o,64));
  return v;
}
__device__ __forceinline__ float blockReduceSum256(float val, float* red){
  __syncthreads();
  val = waveReduceSum(val);
  if((threadIdx.x&63)==0) red[threadIdx.x>>6]=val;
  __syncthreads();
  return red[0]+red[1]+red[2]+red[3];
}
__device__ __forceinline__ float blockReduceMin256(float val, float* red){
  __syncthreads();
  val = waveReduceMin(val);
  if((threadIdx.x&63)==0) red[threadIdx.x>>6]=val;
  __syncthreads();
  return fminf(fminf(red[0],red[1]),fminf(red[2],red[3]));
}
__device__ __forceinline__ float blockReduceMax256(float val, float* red){
  __syncthreads();
  val = waveReduceMax(val);
  if((threadIdx.x&63)==0) red[threadIdx.x>>6]=val;
  __syncthreads();
  return fmaxf(fmaxf(red[0],red[1]),fmaxf(red[2],red[3]));
}

// ---------------------------------------------------------------------------
// Generic strided 2D copy: dst[doff + r*dld + c] = src[soff + r*sld + c]
// ---------------------------------------------------------------------------
__global__ __launch_bounds__(256) void fd_copyblk(
    float* __restrict__ dst, int dld, i64 doff,
    const float* __restrict__ src, int sld, i64 soff,
    int rows, int cols)
{
  i64 tot = (i64)rows*cols;
  for(i64 id = (i64)blockIdx.x*256 + threadIdx.x; id < tot; id += (i64)gridDim.x*256){
    int r = (int)(id / cols), c = (int)(id % cols);
    dst[doff + (i64)r*dld + c] = src[soff + (i64)r*sld + c];
  }
}

// ---------------------------------------------------------------------------
// Column scale: out (rows x 128) = in * diag(w)
// ---------------------------------------------------------------------------
__global__ __launch_bounds__(256) void fd_colscale(
    const float* __restrict__ in, const float* __restrict__ w,
    float* __restrict__ out, int rows)
{
  int tot = rows*128;
  for(int id = blockIdx.x*256 + threadIdx.x; id < tot; id += gridDim.x*256)
    out[id] = in[id] * w[id & 127];
}

// ---------------------------------------------------------------------------
// Generic fp32 GEMM: C = alpha*op(A)op(B) [+C if betaone] [+bias bcast over rows]
// tA: A stored K x M (row-major);  else M x K.  tB: B stored N x K; else K x N.
// grid = (M/64, N/64, kchunks). useAtomic -> atomicAdd into C (pre-zeroed).
// ---------------------------------------------------------------------------
__global__ __launch_bounds__(256) void fd_gemm(
    const float* __restrict__ A, const float* __restrict__ B,
    float* __restrict__ C, const float* __restrict__ bias,
    int M, int N, int K, int lda, int ldb, int ldc,
    int tA, int tB, float alpha, int betaone, int useAtomic)
{
  __shared__ float As[16][68];
  __shared__ float Bs[16][68];
  int bm = blockIdx.x*64, bn = blockIdx.y*64;
  int kchunk = K / gridDim.z;
  int k0 = blockIdx.z * kchunk;
  int tn = threadIdx.x & 15, tm = threadIdx.x >> 4;
  float acc[4][4] = {{0.f}};
  for(int kt = k0; kt < k0 + kchunk; kt += 16){
    if(tA){
      for(int l=threadIdx.x; l<1024; l+=256){ int kk=l>>6, mm=l&63;
        As[kk][mm] = A[(i64)(kt+kk)*lda + bm+mm]; }
    }else{
      for(int l=threadIdx.x; l<1024; l+=256){ int mm=l>>4, kk=l&15;
        As[kk][mm] = A[(i64)(bm+mm)*lda + kt+kk]; }
    }
    if(tB){
      for(int l=threadIdx.x; l<1024; l+=256){ int nn=l>>4, kk=l&15;
        Bs[kk][nn] = B[(i64)(bn+nn)*ldb + kt+kk]; }
    }else{
      for(int l=threadIdx.x; l<1024; l+=256){ int kk=l>>6, nn=l&63;
        Bs[kk][nn] = B[(i64)(kt+kk)*ldb + bn+nn]; }
    }
    __syncthreads();
#pragma unroll
    for(int kk=0; kk<16; kk++){
      float a[4], b[4];
#pragma unroll
      for(int i=0;i<4;i++){ a[i]=As[kk][tm*4+i]; b[i]=Bs[kk][tn*4+i]; }
#pragma unroll
      for(int i=0;i<4;i++)
#pragma unroll
        for(int j=0;j<4;j++) acc[i][j] += a[i]*b[j];
    }
    __syncthreads();
  }
#pragma unroll
  for(int i=0;i<4;i++){
    int row = bm + tm*4 + i;
#pragma unroll
    for(int j=0;j<4;j++){
      int col = bn + tn*4 + j;
      i64 idx = (i64)row*ldc + col;
      float v = alpha*acc[i][j];
      if(useAtomic){ atomicAdd(&C[idx], v); }
      else{
        if(betaone) v += C[idx];
        if(bias)    v += bias[col];
        C[idx] = v;
      }
    }
  }
}

// ---------------------------------------------------------------------------
// Cholesky of a 128x128 SPD block (packed-lower in LDS), regularized.
// ---------------------------------------------------------------------------
__global__ __launch_bounds__(256) void fd_chol128(
    const float* __restrict__ G, int gld, i64 goff,
    float* __restrict__ L, int lld, i64 loff)
{
  __shared__ float P[8256];     // packed lower: row i at i*(i+1)/2
  __shared__ float colv[128];
  __shared__ float sc[2];
  int t = threadIdx.x;
  for(int i=t;i<128;i+=256){
    int base = i*(i+1)/2;
    for(int j=0;j<=i;j++) P[base+j] = G[goff + (i64)i*gld + j];
  }
  __syncthreads();
  if(t==0){
    float m=0.f;
    for(int i=0;i<128;i++){ float dd=P[i*(i+1)/2+i]; if(dd>m) m=dd; }
    if(!(m>0.f)) m = 1e-20f;
    sc[0] = m*4e-6f;   // diagonal regularization
    sc[1] = m*1e-8f;   // pivot floor
  }
  __syncthreads();
  float reg = sc[0], flo = sc[1];
  for(int i=t;i<128;i+=256) P[i*(i+1)/2+i] += reg;
  __syncthreads();
  for(int j=0;j<128;j++){
    int jb = j*(j+1)/2;
    if(t==0){
      float dd = fmaxf(P[jb+j], flo);
      float piv = sqrtf(dd);
      P[jb+j] = piv;
      colv[j] = piv;
    }
    __syncthreads();
    float pr = 1.f/colv[j];
    for(int i=j+1+t; i<128; i+=256){
      int base = i*(i+1)/2;
      float v = P[base+j]*pr;
      P[base+j] = v;
      colv[i] = v;
    }
    __syncthreads();
    for(int i=j+1+t; i<128; i+=256){
      int base = i*(i+1)/2;
      float ci = colv[i];
      for(int kx=j+1; kx<=i; kx++) P[base+kx] -= ci*colv[kx];
    }
    __syncthreads();
  }
  for(int i=t;i<128;i+=256){
    int base = i*(i+1)/2;
    for(int j=0;j<=i;j++)      L[loff + (i64)i*lld + j] = P[base+j];
    for(int j=i+1;j<128;j++)   L[loff + (i64)i*lld + j] = 0.f;
  }
}

// ---------------------------------------------------------------------------
// X = (L^T)^{-1} (upper 128x128, dense row-major). Thread k solves column k.
// L staged into LDS so the serial solve reads LDS, not strided global.
// ---------------------------------------------------------------------------
__global__ __launch_bounds__(128) void fd_trinv128(
    const float* __restrict__ L, int lld, i64 loff, float* __restrict__ X)
{
  __shared__ float Ls[128][129];
  int k = threadIdx.x;
  for(int idx=k; idx<16384; idx+=128){
    int i = idx >> 7, j = idx & 127;
    Ls[i][j] = L[loff + (i64)i*lld + j];
  }
  __syncthreads();
  for(int i=k+1;i<128;i++) X[(i64)i*128 + k] = 0.f;
  X[(i64)k*128 + k] = 1.f / Ls[k][k];
  for(int i=k-1;i>=0;i--){
    float s = 0.f;
    for(int j=i+1;j<=k;j++) s += Ls[j][i] * X[(i64)j*128 + k];
    X[(i64)i*128 + k] = -s / Ls[i][i];
  }
}

// ---------------------------------------------------------------------------
// Householder tridiagonalization of symmetric 256x256 A, fully in LDS.
// Packed lower triangle (256*257/2 floats = 131.6 KB) — fits gfx950's 160 KB.
// Writes d[256], e[256], unit Householder vectors Vh[j][0:256].
// One block, 256 threads (thread t <-> row t). A = Q T Q^T, Q = H_0...H_253.
// ---------------------------------------------------------------------------
__global__ __launch_bounds__(256) void fd_tridiag(
    const float* __restrict__ A, float* __restrict__ dT,
    float* __restrict__ eT, float* __restrict__ Vh)
{
  const int n = 256;
  __shared__ float P[32896];    // packed lower: row i at i*(i+1)/2
  __shared__ float v[256], w[256];
  __shared__ float red[8];
  __shared__ float sc[2];
  int t = threadIdx.x;
  // load lower triangle, coalesced per row
  for(int i=0;i<n;i++){
    int base = i*(i+1)/2;
    for(int j=t;j<=i;j+=256) P[base+j] = A[(i64)i*n + j];
  }
  __syncthreads();
  for(int j=0;j<n-2;j++){
    float xi = (t>j)? P[t*(t+1)/2 + j] : 0.f;
    float nrm2 = blockReduceSum256(xi*xi, red);
    if(t==0){
      float x0 = P[(j+1)*(j+2)/2 + j];
      float nr = sqrtf(nrm2);
      float beta = (x0>=0.f)? -nr : nr;
      eT[j] = beta;
      float vn2 = 2.f*nrm2 - 2.f*beta*x0;
      sc[0]=beta; sc[1] = (vn2>1e-30f)? rsqrtf(vn2) : 0.f;
    }
    __syncthreads();
    float beta=sc[0], vs=sc[1];
    float vt = (t>j)? (xi - ((t==j+1)? beta : 0.f))*vs : 0.f;
    v[t]=vt;
    Vh[(i64)j*n + t] = vt;
    __syncthreads();
    // u = A2 v over trailing symmetric submatrix (rows/cols j+1..n-1):
    // row part from row t, column part from column t (rows below t).
    float ut=0.f;
    if(t>j){
      int base = t*(t+1)/2;
      for(int k=j+1;k<=t;k++) ut += P[base+k]*v[k];
      for(int k=t+1;k<n;k++)  ut += P[k*(k+1)/2 + t]*v[k];
    }
    float gamma = blockReduceSum256(vt*ut, red);
    float wt = 2.f*ut - 2.f*gamma*vt;
    w[t]=wt;
    __syncthreads();
    // rank-2 update of lower trailing: P[t][k] -= v_t w_k + w_t v_k, j<k<=t
    if(t>j){
      int base = t*(t+1)/2;
      float vi=vt, wi=wt;
      for(int k=j+1;k<=t;k++) P[base+k] -= vi*w[k] + wi*v[k];
    }
    __syncthreads();
  }
  dT[t] = P[t*(t+1)/2 + t];
  if(t==0) eT[n-2] = P[(n-1)*n/2 + (n-2)];
  if(t==1) eT[n-1] = 0.f;
}

// ---------------------------------------------------------------------------
// Bisection eigenvalues of tridiagonal T: lam[k] = k-th LARGEST, k=0..128.
// Then shrink weights: wfx[i]=s_i/lambda_i, wfy[i]=s_i/sigma_i.
// ---------------------------------------------------------------------------
__global__ __launch_bounds__(256) void fd_bisect(
    const float* __restrict__ dT, const float* __restrict__ eT,
    float* __restrict__ lam, float* __restrict__ wfx, float* __restrict__ wfy)
{
  __shared__ float d[256], e2[256], eabs[256];
  __shared__ float red[8];
  __shared__ float sgl, sgh, spm, sdel;
  int t = threadIdx.x;
  d[t] = dT[t];
  float ev = (t<255)? eT[t] : 0.f;
  e2[t] = ev*ev; eabs[t] = fabsf(ev);
  __syncthreads();
  float rr = ((t>0)? eabs[t-1] : 0.f) + eabs[t];
  float mn = blockReduceMin256(d[t]-rr, red);
  float mx = blockReduceMax256(d[t]+rr, red);
  if(t==0){
    sgl = mn; sgh = mx;
    float s = fmaxf(fabsf(mn), fabsf(mx));
    spm = fmaxf(1e-25f, 1e-12f*s);
  }
  __syncthreads();
  float glo=sgl, ghi=sgh, pivmin=spm;
  if(t<=128){
    int k = t;
    float lo=glo, hi=ghi;
    for(int it=0; it<42; it++){
      float mid = 0.5f*(lo+hi);
      int cnt=0;
      float q = d[0]-mid; if(q<0.f) cnt++;
      for(int i=1;i<256;i++){
        if(fabsf(q)<pivmin) q = -pivmin;
        q = (d[i]-mid) - e2[i-1]/q;
        if(q<0.f) cnt++;
      }
      if(cnt <= 255-k) lo=mid; else hi=mid;
    }
    lam[k] = lo;
  }
  __syncthreads();
  if(t==0) sdel = sqrtf(fmaxf(lam[128], 0.f));
  __syncthreads();
  if(t<128){
    float l = lam[t];
    float sg = sqrtf(fmaxf(l,0.f));
    float s2 = fmaxf(sg - sdel, 0.f);
    float s = sqrtf(s2);
    wfx[t] = (s2>0.f && l >1e-30f)? (s/l)  : 0.f;
    wfy[t] = (s2>0.f && sg>1e-30f)? (s/sg) : 0.f;
  }
}

// ---------------------------------------------------------------------------
// Inverse iteration (2 passes) for top-128 eigenvectors of tridiagonal T.
// ---------------------------------------------------------------------------
__global__ __launch_bounds__(128) void fd_invit(
    const float* __restrict__ dT, const float* __restrict__ eT,
    const float* __restrict__ lam, float* __restrict__ Ut,
    float* __restrict__ ud, float* __restrict__ ue, float* __restrict__ uf)
{
  __shared__ float d[256], e[256];
  int k = threadIdx.x;
  for(int i=k;i<256;i+=128){ d[i]=dT[i]; e[i]=(i<255)? eT[i] : 0.f; }
  __syncthreads();
  float scl = fmaxf(fabsf(lam[0]), 1e-20f);
  unsigned hh = (unsigned)k*2654435761u; hh ^= hh>>13; hh *= 1103515245u; hh ^= hh>>16;
  float pert = (float)(hh & 0xFFFFu) * (1.f/65536.f);
  float shift = lam[k] - scl*6e-7f*(0.25f + pert);
  float pivmin = 3e-7f*scl + 1e-30f;
#define AT(a,i) a[(i64)(i)*128 + k]
  for(int i=0;i<256;i++){
    unsigned z = ((unsigned)i*73856093u) ^ ((unsigned)k*19349663u);
    z ^= z>>13; z *= 2654435769u; z ^= z>>16;
    AT(Ut,i) = ((float)(z & 0xFFFFFFu) * (1.f/8388608.f)) - 1.f;
  }
  for(int pass=0; pass<2; pass++){
    float p = d[0]-shift, q = e[0], r = 0.f;
    for(int i=0;i<255;i++){
      float bel = e[i];
      float bn  = d[i+1]-shift;
      float cn  = (i+1<255)? e[i+1] : 0.f;
      float xi  = AT(Ut,i), xn = AT(Ut,i+1);
      if(fabsf(p) >= fabsf(bel)){
        float piv = (fabsf(p)<pivmin)? ((p<0.f)?-pivmin:pivmin) : p;
        float m = bel/piv;
        AT(ud,i)=piv; AT(ue,i)=q; AT(uf,i)=r;
        p = bn - m*q; q = cn - m*r; r = 0.f;
        AT(Ut,i+1) = xn - m*xi;
      } else {
        float piv = bel;
        float m = p/piv;
        AT(ud,i)=piv; AT(ue,i)=bn; AT(uf,i)=cn;
        p = q - m*bn; q = r - m*cn; r = 0.f;
        AT(Ut,i) = xn;
        AT(Ut,i+1) = xi - m*xn;
      }
    }
    {
      float piv = (fabsf(p)<pivmin)? ((p<0.f)?-pivmin:pivmin) : p;
      AT(ud,255)=piv;
    }
    float x1=0.f, x2=0.f, nrm2=0.f;
    for(int i=255;i>=0;i--){
      float s = AT(Ut,i);
      if(i<255) s -= AT(ue,i)*x1;
      if(i<254) s -= AT(uf,i)*x2;
      float x = s / AT(ud,i);
      x = fminf(fmaxf(x, -1e17f), 1e17f);
      AT(Ut,i) = x;
      x2=x1; x1=x;
      nrm2 += x*x;
    }
    float rn = rsqrtf(fmaxf(nrm2, 1e-30f));
    for(int i=0;i<256;i++) AT(Ut,i) *= rn;
  }
#undef AT
}

// ---------------------------------------------------------------------------
// Back-transform: Uout = Q * Uin, Q = H_0 ... H_253 (apply j=253..0).
// ---------------------------------------------------------------------------
__global__ __launch_bounds__(256) void fd_applyq(
    const float* __restrict__ Vh, const float* __restrict__ Uin,
    float* __restrict__ Uout)
{
  __shared__ float S[256][33];
  __shared__ float v[256];
  __shared__ float part[8][32];
  __shared__ float wc[32];
  int c = threadIdx.x & 31, g = threadIdx.x >> 5;   // 8 row-groups of 32
  int cb = blockIdx.x*32;
  for(int i=g*32; i<g*32+32; i++) S[i][c] = Uin[(i64)i*128 + cb + c];
  __syncthreads();
  for(int j=253;j>=0;j--){
    v[threadIdx.x] = Vh[(i64)j*256 + threadIdx.x];
    __syncthreads();
    float pd = 0.f;
    for(int i=g*32;i<g*32+32;i++) pd += v[i]*S[i][c];
    part[g][c] = pd;
    __syncthreads();
    if(g==0){
      float s=0.f;
#pragma unroll
      for(int gg=0;gg<8;gg++) s += part[gg][c];
      wc[c] = 2.f*s;
    }
    __syncthreads();
    float wv = wc[c];
    for(int i=g*32;i<g*32+32;i++) S[i][c] -= v[i]*wv;
    __syncthreads();
  }
  for(int i=g*32;i<g*32+32;i++) Uout[(i64)i*128 + cb + c] = S[i][c];
}

// ---------------------------------------------------------------------------
// Host driver
// ---------------------------------------------------------------------------
extern "C" void kernel_launch(void* const* d_in, const int* in_sizes, int n_in,
                              void* d_out, int out_size, void* d_ws, size_t ws_size,
                              hipStream_t stream)
{
  const float* x    = (const float*)d_in[0];   // 8192 x 1280
  const float* wgt  = (const float*)d_in[1];   // 5120 x 1280
  const float* bias = (const float*)d_in[2];   // 5120
  float* out = (float*)d_out;

  const int m = 8192, p = 5120, ldx = 1280, nb = 10;

  // ---- scratch layout: everything dead-before-final lives inside d_out ----
  float* ob = (float*)d_out;
  i64 o = 0;
  float* Cx  = ob+o; o += (i64)m*256;
  float* Cy  = ob+o; o += (i64)p*256;
  float* Gxx = ob+o; o += 65536;
  float* Gyy = ob+o; o += 65536;
  float* Lx  = ob+o; o += 65536;
  float* Ly  = ob+o; o += 65536;
  float* Km  = ob+o; o += 65536;
  float* Am  = ob+o; o += 65536;
  float* Vh  = ob+o; o += 65536;
  float* Ssx = ob+o; o += 16384;
  float* Ssy = ob+o; o += 16384;
  float* Xx  = ob+o; o += 16384;
  float* Xy  = ob+o; o += 16384;
  float* Xq  = ob+o; o += 16384;
  float* G1q = ob+o; o += 16384;
  float* dT  = ob+o; o += 256;
  float* eT  = ob+o; o += 256;
  float* lam = ob+o; o += 256;
  float* wfx = ob+o; o += 128;
  float* wfy = ob+o; o += 128;
  float* Ut  = ob+o; o += 32768;
  float* Uo1 = ob+o; o += 32768;
  float* Uo  = ob+o; o += 32768;
  float* Ub  = ob+o; o += 32768;
  float* Pm  = ob+o; o += 32768;
  float* Pf  = ob+o; o += 32768;
  float* Uf  = ob+o; o += 32768;
  float* Mx  = ob+o; o += 32768;
  float* My  = ob+o; o += 32768;
  float* iud = ob+o; o += 32768;
  float* iue = ob+o; o += 32768;
  float* iuf = ob+o; o += 32768;

  // Bx/By must survive into the final GEMM (which overwrites d_out) -> d_ws
  float* ws = (float*)d_ws;
  float* Bx = ws;                       // 8192 x 128
  float* By = ws + (i64)m*128;          // 5120 x 128
  (void)ws_size; (void)out_size; (void)n_in; (void)in_sizes;

  auto GEMM = [&](const float* A, const float* B, float* C, const float* bs,
                  int M,int N,int K,int lda,int ldb,int ldc,int tA,int tB,
                  float alpha,int betaone,int atom,int kz){
    dim3 g(M/64, N/64, kz);
    hipLaunchKernelGGL(fd_gemm, g, dim3(256), 0, stream,
                       A,B,C,bs,M,N,K,lda,ldb,ldc,tA,tB,alpha,betaone,atom);
  };
  auto COPY = [&](float* dst,int dld,i64 doff,const float* src,int sld,i64 soff,
                  int rows,int cols){
    i64 tot=(i64)rows*cols; int g=(int)((tot+255)/256); if(g>4096) g=4096;
    hipLaunchKernelGGL(fd_copyblk, dim3(g), dim3(256), 0, stream,
                       dst,dld,doff,src,sld,soff,rows,cols);
  };
  auto Z = [&](float* ptr, i64 elems){ hipMemsetAsync(ptr, 0, (size_t)elems*4, stream); };

  for(int t=1;t<nb;t++){
    // ---- pack Cx = [Bx | x_t], Cy = [By | w_t] (step 1: Bx=x_0, By=w_0) ----
    if(t==1){ COPY(Cx,256,0, x,  ldx,0, m,128); COPY(Cy,256,0, wgt,ldx,0, p,128); }
    else    { COPY(Cx,256,0, Bx, 128,0, m,128); COPY(Cy,256,0, By, 128,0, p,128); }
    COPY(Cx,256,128, x,  ldx,(i64)t*128, m,128);
    COPY(Cy,256,128, wgt,ldx,(i64)t*128, p,128);

    // ---- Grams (split-K + atomics) ----
    Z(Gxx,65536); Z(Gyy,65536);
    GEMM(Cx,Cx,Gxx,nullptr, 256,256,8192, 256,256,256, 1,0, 1.f,0,1, 8);
    GEMM(Cy,Cy,Gyy,nullptr, 256,256,5120, 256,256,256, 1,0, 1.f,0,1, 5);

    // ---- blocked 256-Cholesky, x side: Gxx = Lx Lx^T ----
    Z(Lx,65536);
    hipLaunchKernelGGL(fd_chol128, dim3(1),dim3(256),0,stream, Gxx,256,(i64)0, Lx,256,(i64)0);
    hipLaunchKernelGGL(fd_trinv128,dim3(1),dim3(128),0,stream, Lx,256,(i64)0, Xx);
    GEMM(Gxx + (i64)128*256, Xx, Lx + (i64)128*256, nullptr,
         128,128,128, 256,128,256, 0,0, 1.f,0,0, 1);                 // L21 = G21 * (L11^T)^-1
    COPY(Ssx,128,0, Gxx,256,(i64)128*256+128, 128,128);              // S = G22
    GEMM(Lx + (i64)128*256, Lx + (i64)128*256, Ssx, nullptr,
         128,128,128, 256,256,128, 0,1, -1.f,1,0, 1);                // S -= L21 L21^T
    hipLaunchKernelGGL(fd_chol128, dim3(1),dim3(256),0,stream, Ssx,128,(i64)0,
                       Lx,256,(i64)128*256+128);

    // ---- y side: Gyy = Ly Ly^T ----
    Z(Ly,65536);
    hipLaunchKernelGGL(fd_chol128, dim3(1),dim3(256),0,stream, Gyy,256,(i64)0, Ly,256,(i64)0);
    hipLaunchKernelGGL(fd_trinv128,dim3(1),dim3(128),0,stream, Ly,256,(i64)0, Xy);
    GEMM(Gyy + (i64)128*256, Xy, Ly + (i64)128*256, nullptr,
         128,128,128, 256,128,256, 0,0, 1.f,0,0, 1);
    COPY(Ssy,128,0, Gyy,256,(i64)128*256+128, 128,128);
    GEMM(Ly + (i64)128*256, Ly + (i64)128*256, Ssy, nullptr,
         128,128,128, 256,256,128, 0,1, -1.f,1,0, 1);
    hipLaunchKernelGGL(fd_chol128, dim3(1),dim3(256),0,stream, Ssy,128,(i64)0,
                       Ly,256,(i64)128*256+128);

    // ---- core K = Rx Ry^T = Lx^T Ly ;  A = K K^T ----
    GEMM(Lx,Ly,Km,nullptr, 256,256,256, 256,256,256, 1,0, 1.f,0,0, 1);
    GEMM(Km,Km,Am,nullptr, 256,256,256, 256,256,256, 0,1, 1.f,0,0, 1);

    // ---- EVD of A: tridiag (LDS) -> bisection -> inverse iteration ----
    hipLaunchKernelGGL(fd_tridiag, dim3(1),dim3(256),0,stream, Am,dT,eT,Vh);
    hipLaunchKernelGGL(fd_bisect,  dim3(1),dim3(256),0,stream, dT,eT,lam,wfx,wfy);
    hipLaunchKernelGGL(fd_invit,   dim3(1),dim3(128),0,stream, dT,eT,lam,Ut,iud,iue,iuf);

    // ---- CholQR2 on the 128 top T-basis vectors ----
    GEMM(Ut,Ut,G1q,nullptr, 128,128,256, 128,128,128, 1,0, 1.f,0,0, 1);
    hipLaunchKernelGGL(fd_chol128, dim3(1),dim3(256),0,stream, G1q,128,(i64)0, Ssx,128,(i64)0);
    hipLaunchKernelGGL(fd_trinv128,dim3(1),dim3(128),0,stream, Ssx,128,(i64)0, Xq);
    GEMM(Ut,Xq,Uo1,nullptr, 256,128,128, 128,128,128, 0,0, 1.f,0,0, 1);
    GEMM(Uo1,Uo1,G1q,nullptr, 128,128,256, 128,128,128, 1,0, 1.f,0,0, 1);
    hipLaunchKernelGGL(fd_chol128, dim3(1),dim3(256),0,stream, G1q,128,(i64)0, Ssx,128,(i64)0);
    hipLaunchKernelGGL(fd_trinv128,dim3(1),dim3(128),0,stream, Ssx,128,(i64)0, Xq);
    GEMM(Uo1,Xq,Uo,nullptr, 256,128,128, 128,128,128, 0,0, 1.f,0,0, 1);

    // ---- back-transform to original basis: Ub = Q_H * Uo ----
    hipLaunchKernelGGL(fd_applyq, dim3(4),dim3(256),0,stream, Vh,Uo,Ub);

    // ---- coefficient updates (all GEMMs, no triangular solves) ----
    GEMM(Km,Ub,Pm,nullptr, 256,128,256, 256,128,128, 1,0, 1.f,0,0, 1);   // P = K^T U
    hipLaunchKernelGGL(fd_colscale, dim3(128),dim3(256),0,stream, Pm,wfx,Pf,256);
    hipLaunchKernelGGL(fd_colscale, dim3(128),dim3(256),0,stream, Ub,wfy,Uf,256);
    GEMM(Ly,Pf,Mx,nullptr, 256,128,256, 256,128,128, 0,0, 1.f,0,0, 1);   // Mx = Ry^T P diag
    GEMM(Lx,Uf,My,nullptr, 256,128,256, 256,128,128, 0,0, 1.f,0,0, 1);   // My = Rx^T U diag

    GEMM(Cx,Mx,Bx,nullptr, 8192,128,256, 256,128,128, 0,0, 1.f,0,0, 1);  // Bx' = Cx Mx
    GEMM(Cy,My,By,nullptr, 5120,128,256, 256,128,128, 0,0, 1.f,0,0, 1);  // By' = Cy My
  }

  // ---- final: out = Bx By^T + bias (overwrites all of d_out) ----
  GEMM(Bx,By,out,bias, 8192,5120,128, 128,128,5120, 0,1, 1.f,0,0, 1);
}